// Round 1
// baseline (586.379 us; speedup 1.0000x reference)
//
#include <hip/hip_runtime.h>

#define NN 512
#define MROWS (NN*NN)        // 262144

typedef __attribute__((ext_vector_type(8))) short short8;
typedef __attribute__((ext_vector_type(16))) float floatx16;

__device__ __forceinline__ unsigned short f2bf(float f) {
    union { float f; unsigned u; } x; x.f = f;
    unsigned r = x.u + 0x7fffu + ((x.u >> 16) & 1u);
    return (unsigned short)(r >> 16);
}

__device__ __forceinline__ unsigned pack2bf(float a, float b) {
    return (unsigned)f2bf(a) | ((unsigned)f2bf(b) << 16);
}

__device__ __forceinline__ floatx16 zero16() {
    floatx16 z;
    #pragma unroll
    for (int i = 0; i < 16; ++i) z[i] = 0.f;
    return z;
}

// ---------------- pre: proj (blocks 0..1023) + weight bf16 convert (1024..1535) ----------------
__global__ __launch_bounds__(256) void pre_kernel(
    const float* __restrict__ q, const float* __restrict__ k,
    const float* __restrict__ Wq, const float* __restrict__ bq,
    const float* __restrict__ Wk, const float* __restrict__ bk,
    float* __restrict__ pq, float* __restrict__ pk,
    const float* __restrict__ Wb, const float* __restrict__ Wbo,
    unsigned short* __restrict__ wbf)
{
    int b = blockIdx.x;
    int tid = threadIdx.x;
    if (b >= 1024) {
        int i = (b - 1024) * 256 + tid;          // 131072 elems
        float v = (i < 65536) ? Wb[i] : Wbo[i - 65536];
        wbf[i] = f2bf(v);
        return;
    }
    __shared__ float xs[64];
    int n = b & 511;
    int is_k = b >> 9;
    const float* x  = is_k ? k  : q;
    const float* W  = is_k ? Wk : Wq;
    const float* bi = is_k ? bk : bq;
    float* out      = is_k ? pk : pq;
    if (tid < 16)
        reinterpret_cast<float4*>(xs)[tid] = reinterpret_cast<const float4*>(x + n*64)[tid];
    __syncthreads();
    #pragma unroll
    for (int jj = 0; jj < 2; ++jj) {
        int j = jj*256 + tid;
        const float4* wr = reinterpret_cast<const float4*>(W + j*64);
        float acc = bi[j];
        #pragma unroll
        for (int c = 0; c < 16; ++c) {
            float4 w4 = wr[c];
            float4 x4 = reinterpret_cast<const float4*>(xs)[c];
            acc += x4.x*w4.x + x4.y*w4.y + x4.z*w4.z + x4.w*w4.w;
        }
        out[n*512 + j] = acc;
    }
}

// ---------------- fused bias path v3: barrier-free, wave-private 32-row tiles, zero LDS ----------------
// Each wave owns 32 rows (m). Key facts of mfma_f32_32x32x16_bf16:
//   B-operand row = lane&31 (every k-step)  -> bias tile lives in 32 VGPRs/lane, no lA.
//   C/D column   = lane&31 = m              -> P rows needed by phase2 are lane-local, no lP.
// Cross-half (n1 bit2) exchange done with __shfl_xor(,32) on packed bf16 pairs.
__global__ __launch_bounds__(256, 2) void bias_kernel(
    const float* __restrict__ bias, const unsigned short* __restrict__ wb_bf,
    const float* __restrict__ bb, const unsigned short* __restrict__ wbo_bf,
    const float* __restrict__ bbo, float* __restrict__ bias_out,
    float* __restrict__ diffs)
{
    const int tid = threadIdx.x;
    const int w   = tid >> 6;          // wave id: owns rows w*32..w*32+31 of this block's 128
    const int l   = tid & 63;
    const int l31 = l & 31;
    const int qh  = l >> 5;            // lane half: provides k-elements qh*8..qh*8+7 of each 16-slice
    const long row = (long)blockIdx.x * 128 + w*32 + l31;   // this lane's bias row (m)

    // ---- load this lane's bias row as 8 bf16 fragments (covers cols kk*16+qh*8, kk=0..7) ----
    short8 bias_fr[8];
    {
        const float* brow = bias + row*128 + qh*8;
        #pragma unroll
        for (int kk = 0; kk < 8; ++kk) {
            float4 v0 = *reinterpret_cast<const float4*>(brow + kk*16);
            float4 v1 = *reinterpret_cast<const float4*>(brow + kk*16 + 4);
            short8 t;
            t[0] = (short)f2bf(v0.x); t[1] = (short)f2bf(v0.y);
            t[2] = (short)f2bf(v0.z); t[3] = (short)f2bf(v0.w);
            t[4] = (short)f2bf(v1.x); t[5] = (short)f2bf(v1.y);
            t[6] = (short)f2bf(v1.z); t[7] = (short)f2bf(v1.w);
            bias_fr[kk] = t;
        }
    }

    floatx16 acc2[4];                  // C2^T[n2-tile][.]: n2 = nt2*32 + r+8s+4qh, m = l31
    acc2[0] = zero16(); acc2[1] = zero16(); acc2[2] = zero16(); acc2[3] = zero16();

    const unsigned short* wbbase  = wb_bf  + l31*128 + qh*8;   // Wb row (h*128+nt*32+l31)
    const unsigned short* wbobase = wbo_bf + l31*512 + qh*8;   // Wbo row (nt2*32+l31)

    for (int h = 0; h < 4; ++h) {
        // ---- phase 1: C1^T[n1][m] = Wb_h . bias^T  (full n1=128 per wave) ----
        floatx16 acc1[4];
        acc1[0] = zero16(); acc1[1] = zero16(); acc1[2] = zero16(); acc1[3] = zero16();
        const unsigned short* wh = wbbase + h*16384;
        #pragma unroll
        for (int kk = 0; kk < 8; ++kk) {
            #pragma unroll
            for (int nt = 0; nt < 4; ++nt) {
                short8 afr = *reinterpret_cast<const short8*>(wh + nt*4096 + kk*16);
                acc1[nt] = __builtin_amdgcn_mfma_f32_32x32x16_bf16(afr, bias_fr[kk], acc1[nt], 0, 0, 0);
            }
        }

        // ---- epilogue: +bb, lane-local sumsq, pack P to bf16 B-fragments in-register ----
        // Lane holds C1 value (n1 = nt*32 + 8s + 4qh + r, m = l31) in acc1[nt][s*4+r].
        // Phase2 B-fragment kk2: lane needs P[m=l31][n1 = kk2*16 + qh*8 + e], e=0..7,
        //   = { (s=s0+qh, r=0..3) from half0 , same from half1 },  nt = kk2>>1, s0 = (kk2&1)*2.
        float ssq = 0.f;
        short8 bfr[8];
        #pragma unroll
        for (int kk2 = 0; kk2 < 8; ++kk2) {
            const int nt = kk2 >> 1, s0 = (kk2 & 1) * 2;
            unsigned a0, b0, a1, b1;
            #pragma unroll
            for (int si = 0; si < 2; ++si) {
                const int s = s0 + si;
                float4 bb4 = *reinterpret_cast<const float4*>(bb + h*128 + nt*32 + s*8 + qh*4);
                float v0 = acc1[nt][s*4+0] + bb4.x;
                float v1 = acc1[nt][s*4+1] + bb4.y;
                float v2 = acc1[nt][s*4+2] + bb4.z;
                float v3 = acc1[nt][s*4+3] + bb4.w;
                ssq += v0*v0 + v1*v1 + v2*v2 + v3*v3;
                unsigned pa = pack2bf(v0, v1);
                unsigned pb = pack2bf(v2, v3);
                if (si == 0) { a0 = pa; b0 = pb; } else { a1 = pa; b1 = pb; }
            }
            // half exchange: w0/w1 = (s0+qh) packs from half0, w2/w3 = same from half1
            unsigned sa0 = __shfl_xor(a0, 32), sb0 = __shfl_xor(b0, 32);
            unsigned sa1 = __shfl_xor(a1, 32), sb1 = __shfl_xor(b1, 32);
            union { unsigned u[4]; short8 v; } cv;
            cv.u[0] = qh ? sa1 : a0;
            cv.u[1] = qh ? sb1 : b0;
            cv.u[2] = qh ? a1  : sa0;
            cv.u[3] = qh ? b1  : sb0;
            bfr[kk2] = cv.v;
        }
        ssq += __shfl_xor(ssq, 32);
        if (l < 32) diffs[(long)h*MROWS + row] = sqrtf(ssq);

        // ---- phase 2: C2^T[n2][m] += Wbo_h . P_h^T ----
        const unsigned short* wo = wbobase + h*128;
        #pragma unroll
        for (int kk2 = 0; kk2 < 8; ++kk2) {
            #pragma unroll
            for (int nt2 = 0; nt2 < 4; ++nt2) {
                short8 afr = *reinterpret_cast<const short8*>(wo + nt2*16384 + kk2*16);
                acc2[nt2] = __builtin_amdgcn_mfma_f32_32x32x16_bf16(afr, bfr[kk2], acc2[nt2], 0, 0, 0);
            }
        }
    }

    // ---- final epilogue: +bbo, mish, direct float4 stores (row-local, L2 write-combines) ----
    float* orow = bias_out + row*128;
    #pragma unroll
    for (int nt2 = 0; nt2 < 4; ++nt2) {
        #pragma unroll
        for (int s = 0; s < 4; ++s) {
            float4 bo4 = *reinterpret_cast<const float4*>(bbo + nt2*32 + s*8 + qh*4);
            const float* bp = (const float*)&bo4;
            float o[4];
            #pragma unroll
            for (int r = 0; r < 4; ++r) {
                float x = acc2[nt2][s*4+r] + bp[r];
                float e = __expf(x);
                float u = 1.f + e, u2 = u*u;
                o[r] = (x > 15.f) ? x : x * (u2 - 1.f) / (u2 + 1.f);
            }
            float4 ov = { o[0], o[1], o[2], o[3] };
            *reinterpret_cast<float4*>(orow + nt2*32 + s*8 + qh*4) = ov;
        }
    }
}

// ---------------- QK^T logits (in-place over diffs): logits = pq.pk/sqrt(D) + diffs ----------------
__global__ __launch_bounds__(256) void qk_kernel(
    const float* __restrict__ pq, const float* __restrict__ pk,
    float* __restrict__ logits)
{
    __shared__ float A[64*128];
    __shared__ float BT[128*64];
    int blk = blockIdx.x;
    int kt = blk & 7, h = (blk >> 3) & 3, qt = blk >> 5;
    int tid = threadIdx.x;

    #pragma unroll
    for (int i = 0; i < 8; ++i) {
        int flat = i*1024 + tid*4;
        int r = flat >> 7, c = flat & 127;
        *reinterpret_cast<float4*>(&A[flat]) =
            *reinterpret_cast<const float4*>(pq + (size_t)(qt*64 + r)*512 + h*128 + c);
    }
    {
        int kk = tid & 63, g = tid >> 6;
        #pragma unroll
        for (int i = 0; i < 8; ++i) {
            int d0 = g*32 + i*4;
            float4 vv = *reinterpret_cast<const float4*>(pk + (size_t)(kt*64 + kk)*512 + h*128 + d0);
            BT[(d0+0)*64 + kk] = vv.x;
            BT[(d0+1)*64 + kk] = vv.y;
            BT[(d0+2)*64 + kk] = vv.z;
            BT[(d0+3)*64 + kk] = vv.w;
        }
    }
    __syncthreads();

    int qg = tid >> 4, kg = tid & 15;
    int qs = qg*4, ks = kg*4;
    float acc[4][4] = {};
    for (int d = 0; d < 128; d += 4) {
        float a_[4][4], b_[4][4];
        #pragma unroll
        for (int i = 0; i < 4; ++i) {
            float4 av = *reinterpret_cast<const float4*>(&A[(qs+i)*128 + d]);
            a_[i][0] = av.x; a_[i][1] = av.y; a_[i][2] = av.z; a_[i][3] = av.w;
        }
        #pragma unroll
        for (int dd = 0; dd < 4; ++dd) {
            float4 bv = *reinterpret_cast<const float4*>(&BT[(d+dd)*64 + ks]);
            b_[dd][0] = bv.x; b_[dd][1] = bv.y; b_[dd][2] = bv.z; b_[dd][3] = bv.w;
        }
        #pragma unroll
        for (int i = 0; i < 4; ++i)
            #pragma unroll
            for (int j = 0; j < 4; ++j)
                acc[i][j] += a_[i][0]*b_[0][j] + a_[i][1]*b_[1][j]
                           + a_[i][2]*b_[2][j] + a_[i][3]*b_[3][j];
    }

    const float scale = 0.088388347648318447f;   // 1/sqrt(128)
    #pragma unroll
    for (int i = 0; i < 4; ++i) {
        size_t off = (size_t)h*MROWS + (size_t)(qt*64 + qs + i)*512 + kt*64 + ks;
        float4* p = reinterpret_cast<float4*>(logits + off);
        float4 dv = *p;
        dv.x = fmaf(acc[i][0], scale, dv.x);
        dv.y = fmaf(acc[i][1], scale, dv.y);
        dv.z = fmaf(acc[i][2], scale, dv.z);
        dv.w = fmaf(acc[i][3], scale, dv.w);
        *p = dv;
    }
}

// ---------------- softmax + v reduction -> vals_mean ----------------
__global__ __launch_bounds__(256) void attnval_kernel(
    const float* __restrict__ logits, const float* __restrict__ v,
    float* __restrict__ vmean)
{
    __shared__ float red[32];
    int qrow = blockIdx.x, tid = threadIdx.x;
    int wid = tid >> 6;
    float vsum = 0.f;
    float v0 = v[tid], v1 = v[tid + 256];
    for (int h = 0; h < 4; ++h) {
        const float* lr = logits + (size_t)h*MROWS + (size_t)qrow*512;
        float l0 = lr[tid], l1 = lr[tid + 256];
        float m = fmaxf(l0, l1);
        #pragma unroll
        for (int o = 1; o < 64; o <<= 1) m = fmaxf(m, __shfl_xor(m, o));
        if ((tid & 63) == 0) red[wid] = m;
        __syncthreads();
        m = fmaxf(fmaxf(red[0], red[1]), fmaxf(red[2], red[3]));
        float e0 = __expf(l0 - m), e1 = __expf(l1 - m);
        float s = e0 + e1;
        float sv = e0*v0 + e1*v1;
        #pragma unroll
        for (int o = 1; o < 64; o <<= 1) { s += __shfl_xor(s, o); sv += __shfl_xor(sv, o); }
        __syncthreads();
        if ((tid & 63) == 0) { red[8 + wid] = s; red[16 + wid] = sv; }
        __syncthreads();
        float S  = red[8]  + red[9]  + red[10] + red[11];
        float SV = red[16] + red[17] + red[18] + red[19];
        vsum += SV / S;
        __syncthreads();
    }
    if (tid == 0) vmean[qrow] = vsum * 0.25f;
}

// ---------------- q_new/k_new: layernorm(x + mish(p_flat @ W.T + b)) ----------------
__global__ __launch_bounds__(256) void qkout_kernel(
    const float* __restrict__ p, const float* __restrict__ x,
    const float* __restrict__ W, const float* __restrict__ bo,
    const float* __restrict__ g, const float* __restrict__ be,
    float* __restrict__ out)
{
    __shared__ float pr[512];
    __shared__ float red[256];
    int n = blockIdx.x, tid = threadIdx.x;
    if (tid < 128)
        reinterpret_cast<float4*>(pr)[tid] = reinterpret_cast<const float4*>(p + (size_t)n*512)[tid];
    __syncthreads();
    int o = tid >> 2, part = tid & 3;
    const float4* wr = reinterpret_cast<const float4*>(W + o*512 + part*128);
    float acc = 0.f;
    #pragma unroll
    for (int c = 0; c < 32; ++c) {
        float4 w4 = wr[c];
        int base = part*32 + c;
        acc += pr[base]*w4.x + pr[128 + base]*w4.y + pr[256 + base]*w4.z + pr[384 + base]*w4.w;
    }
    red[tid] = acc;
    __syncthreads();
    if (tid < 64) {
        float s = red[tid*4] + red[tid*4+1] + red[tid*4+2] + red[tid*4+3] + bo[tid];
        float e = __expf(s);
        float u = 1.f + e, u2 = u*u;
        float msh = (s > 15.f) ? s : s * (u2 - 1.f) / (u2 + 1.f);
        float val = x[n*64 + tid] + msh;
        float m = val, m2 = val*val;
        #pragma unroll
        for (int off = 1; off < 64; off <<= 1) { m += __shfl_xor(m, off); m2 += __shfl_xor(m2, off); }
        m *= (1.f/64.f); m2 *= (1.f/64.f);
        float var = m2 - m*m;
        out[n*64 + tid] = (val - m) * rsqrtf(var + 1e-5f) * g[tid] + be[tid];
    }
}

extern "C" void kernel_launch(void* const* d_in, const int* in_sizes, int n_in,
                              void* d_out, int out_size, void* d_ws, size_t ws_size,
                              hipStream_t stream) {
    const float* q    = (const float*)d_in[0];
    const float* k    = (const float*)d_in[1];
    const float* v    = (const float*)d_in[2];
    const float* bias = (const float*)d_in[3];
    const float* Wq   = (const float*)d_in[4];
    const float* bq   = (const float*)d_in[5];
    const float* Wk   = (const float*)d_in[6];
    const float* bk   = (const float*)d_in[7];
    const float* Wqo  = (const float*)d_in[8];
    const float* bqo  = (const float*)d_in[9];
    const float* Wko  = (const float*)d_in[10];
    const float* bko  = (const float*)d_in[11];
    const float* qlg  = (const float*)d_in[12];
    const float* qlb  = (const float*)d_in[13];
    const float* klg  = (const float*)d_in[14];
    const float* klb  = (const float*)d_in[15];
    const float* Wb   = (const float*)d_in[16];
    const float* bb   = (const float*)d_in[17];
    const float* Wbo  = (const float*)d_in[18];
    const float* bbo  = (const float*)d_in[19];

    float* out = (float*)d_out;
    float* ws  = (float*)d_ws;
    float* diffs = ws;                                   // 4*262144 fp32 (also logits, in place)
    float* pq    = ws + 4*MROWS;                         // 262144
    float* pk    = pq + MROWS;                           // 262144
    unsigned short* wbf = (unsigned short*)(pk + MROWS); // 131072 bf16 (Wb | Wbo)

    float* q_new = out;             // 512*64
    float* k_new = out + 32768;     // 512*64
    float* vmean = out + 65536;     // 512
    float* b_out = out + 66048;     // 512*512*128

    pre_kernel<<<dim3(1536), dim3(256), 0, stream>>>(q, k, Wq, bq, Wk, bk, pq, pk, Wb, Wbo, wbf);
    bias_kernel<<<dim3(2048), dim3(256), 0, stream>>>(bias, wbf, bb, wbf + 65536, bbo, b_out, diffs);
    qk_kernel<<<dim3(256), dim3(256), 0, stream>>>(pq, pk, diffs);
    attnval_kernel<<<dim3(512), dim3(256), 0, stream>>>(diffs, v, vmean);
    qkout_kernel<<<dim3(512), dim3(256), 0, stream>>>(pq, q, Wqo, bqo, qlg, qlb, q_new);
    qkout_kernel<<<dim3(512), dim3(256), 0, stream>>>(pk, k, Wko, bko, klg, klb, k_new);
}

// Round 2
// 471.740 us; speedup vs baseline: 1.2430x; 1.2430x over previous
//
#include <hip/hip_runtime.h>

#define NN 512
#define MROWS (NN*NN)        // 262144
#define LDK 136              // padded row stride (128 + 8), 16B-aligned rows

typedef __attribute__((ext_vector_type(8))) short short8;
typedef __attribute__((ext_vector_type(16))) float floatx16;

__device__ __forceinline__ unsigned short f2bf(float f) {
    union { float f; unsigned u; } x; x.f = f;
    unsigned r = x.u + 0x7fffu + ((x.u >> 16) & 1u);
    return (unsigned short)(r >> 16);
}

__device__ __forceinline__ floatx16 zero16() {
    floatx16 z;
    #pragma unroll
    for (int i = 0; i < 16; ++i) z[i] = 0.f;
    return z;
}

// ---------------- pre: proj (blocks 0..1023) + weight bf16 convert (1024..1535) ----------------
__global__ __launch_bounds__(256) void pre_kernel(
    const float* __restrict__ q, const float* __restrict__ k,
    const float* __restrict__ Wq, const float* __restrict__ bq,
    const float* __restrict__ Wk, const float* __restrict__ bk,
    float* __restrict__ pq, float* __restrict__ pk,
    const float* __restrict__ Wb, const float* __restrict__ Wbo,
    unsigned short* __restrict__ wbf)
{
    int b = blockIdx.x;
    int tid = threadIdx.x;
    if (b >= 1024) {
        int i = (b - 1024) * 256 + tid;          // 131072 elems
        float v = (i < 65536) ? Wb[i] : Wbo[i - 65536];
        wbf[i] = f2bf(v);
        return;
    }
    __shared__ float xs[64];
    int n = b & 511;
    int is_k = b >> 9;
    const float* x  = is_k ? k  : q;
    const float* W  = is_k ? Wk : Wq;
    const float* bi = is_k ? bk : bq;
    float* out      = is_k ? pk : pq;
    if (tid < 16)
        reinterpret_cast<float4*>(xs)[tid] = reinterpret_cast<const float4*>(x + n*64)[tid];
    __syncthreads();
    #pragma unroll
    for (int jj = 0; jj < 2; ++jj) {
        int j = jj*256 + tid;
        const float4* wr = reinterpret_cast<const float4*>(W + j*64);
        float acc = bi[j];
        #pragma unroll
        for (int c = 0; c < 16; ++c) {
            float4 w4 = wr[c];
            float4 x4 = reinterpret_cast<const float4*>(xs)[c];
            acc += x4.x*w4.x + x4.y*w4.y + x4.z*w4.z + x4.w*w4.w;
        }
        out[n*512 + j] = acc;
    }
}

// ---------------- fused bias path v4: v2 structure + register-prefetched weights ----------------
// v2 diagnosis: VGPR=64 left no headroom -> compiler serialized the 8 per-phase weight
// loads (~250 cyc L2 each) -> MfmaUtil 14%. Fix: explicit 8-fragment prefetch array,
// launch_bounds (256,3) to allow ~160 regs (3 waves/SIMD). Wbo prefetch is issued
// BEFORE the epilogue+barriers so its latency hides under them.
__global__ __launch_bounds__(256, 3) void bias_kernel(
    const float* __restrict__ bias, const unsigned short* __restrict__ wb_bf,
    const float* __restrict__ bb, const unsigned short* __restrict__ wbo_bf,
    const float* __restrict__ bbo, float* __restrict__ bias_out,
    float* __restrict__ diffs)
{
    __shared__ __align__(16) char smem[34816 + 256];
    unsigned short* lA = (unsigned short*)smem;            // [64][LDK] bias tile bf16
    unsigned short* lP = (unsigned short*)(smem + 17408);  // [64][LDK] P chunk bf16
    float* sq = (float*)(smem + 34816);                    // [64]
    float* lT = (float*)smem;                              // [64][LDK] fp32 (epilogue reuse)

    const int tid = threadIdx.x;
    const int w   = tid >> 6;          // wave id -> n1/n2 slice w*32
    const int l   = tid & 63;
    const int l31 = l & 31;
    const int qh  = l >> 5;            // lane half
    const long row0 = (long)blockIdx.x * 64;

    // stage bias tile 64x128 fp32 -> bf16 into lA; zero sq
    {
        const float* src = bias + row0 * 128;
        #pragma unroll
        for (int i = 0; i < 4; ++i) {
            int flat = i*2048 + tid*8;
            int r = flat >> 7, c = flat & 127;
            float4 v0 = *reinterpret_cast<const float4*>(src + flat);
            float4 v1 = *reinterpret_cast<const float4*>(src + flat + 4);
            ushort4 o0 = { f2bf(v0.x), f2bf(v0.y), f2bf(v0.z), f2bf(v0.w) };
            ushort4 o1 = { f2bf(v1.x), f2bf(v1.y), f2bf(v1.z), f2bf(v1.w) };
            *reinterpret_cast<ushort4*>(&lA[r*LDK + c])     = o0;
            *reinterpret_cast<ushort4*>(&lA[r*LDK + c + 4]) = o1;
        }
        if (tid < 64) sq[tid] = 0.f;
    }

    floatx16 acc2[2];
    acc2[0] = zero16(); acc2[1] = zero16();

    // per-lane global weight bases (rows contiguous in k)
    const unsigned short* wbbase  = wb_bf  + (w*32 + l31)*128 + qh*8;   // Wb row n1 (+h*16384 per h)
    const unsigned short* wbobase = wbo_bf + (w*32 + l31)*512 + qh*8;   // Wbo row n2 (+h*128 per h)

    __syncthreads();

    for (int h = 0; h < 4; ++h) {
        // ---- prefetch phase-1 weights (8 x 16B, pipelined) ----
        short8 wpre[8];
        {
            const unsigned short* wa = wbbase + h*16384;
            #pragma unroll
            for (int kk = 0; kk < 8; ++kk)
                wpre[kk] = *reinterpret_cast<const short8*>(wa + kk*16);
        }

        // ---- phase 1: C1^T[n1][m] = Wb_h . bias^T ----
        floatx16 acc1[2];
        acc1[0] = zero16(); acc1[1] = zero16();
        #pragma unroll
        for (int kk = 0; kk < 8; ++kk) {
            short8 b0  = *reinterpret_cast<const short8*>(&lA[(l31)*LDK      + kk*16 + qh*8]);
            short8 b1  = *reinterpret_cast<const short8*>(&lA[(32 + l31)*LDK + kk*16 + qh*8]);
            acc1[0] = __builtin_amdgcn_mfma_f32_32x32x16_bf16(wpre[kk], b0, acc1[0], 0, 0, 0);
            acc1[1] = __builtin_amdgcn_mfma_f32_32x32x16_bf16(wpre[kk], b1, acc1[1], 0, 0, 0);
        }

        // ---- prefetch phase-2 weights NOW: latency hides under epilogue + barriers ----
        {
            const unsigned short* wo = wbobase + h*128;
            #pragma unroll
            for (int kk = 0; kk < 8; ++kk)
                wpre[kk] = *reinterpret_cast<const short8*>(wo + kk*16);
        }

        // ---- epilogue: +bb, lane-local sumsq, bf16 pack ----
        float4 bbq[4];
        #pragma unroll
        for (int s = 0; s < 4; ++s)
            bbq[s] = *reinterpret_cast<const float4*>(bb + h*128 + w*32 + qh*4 + s*8);

        float ssum[2];
        ushort4 pk4[2][4];
        #pragma unroll
        for (int nt = 0; nt < 2; ++nt) {
            float sa = 0.f;
            #pragma unroll
            for (int s = 0; s < 4; ++s) {
                const float* bbp = (const float*)&bbq[s];
                float v0 = acc1[nt][s*4+0] + bbp[0];
                float v1 = acc1[nt][s*4+1] + bbp[1];
                float v2 = acc1[nt][s*4+2] + bbp[2];
                float v3 = acc1[nt][s*4+3] + bbp[3];
                sa += v0*v0 + v1*v1 + v2*v2 + v3*v3;
                pk4[nt][s] = (ushort4){ f2bf(v0), f2bf(v1), f2bf(v2), f2bf(v3) };
            }
            sa += __shfl_xor(sa, 32);
            ssum[nt] = sa;
        }

        __syncthreads();   // B1: prev phase2 lP reads done; sq zero visible

        #pragma unroll
        for (int nt = 0; nt < 2; ++nt) {
            int m = nt*32 + l31;
            #pragma unroll
            for (int s = 0; s < 4; ++s)
                *reinterpret_cast<ushort4*>(&lP[m*LDK + w*32 + qh*4 + s*8]) = pk4[nt][s];
            if (l < 32) atomicAdd(&sq[m], ssum[nt]);
        }

        __syncthreads();   // B2: lP + sq complete

        if (tid < 64) {
            float s2 = sq[tid];
            diffs[(long)h*MROWS + row0 + tid] = sqrtf(s2);
            sq[tid] = 0.f;                     // ready for next h
        }

        // ---- phase 2: C2^T[n2][m] += Wbo_h . P_h^T (weights already in regs) ----
        #pragma unroll
        for (int kk = 0; kk < 8; ++kk) {
            short8 b0  = *reinterpret_cast<const short8*>(&lP[(l31)*LDK      + kk*16 + qh*8]);
            short8 b1  = *reinterpret_cast<const short8*>(&lP[(32 + l31)*LDK + kk*16 + qh*8]);
            acc2[0] = __builtin_amdgcn_mfma_f32_32x32x16_bf16(wpre[kk], b0, acc2[0], 0, 0, 0);
            acc2[1] = __builtin_amdgcn_mfma_f32_32x32x16_bf16(wpre[kk], b1, acc2[1], 0, 0, 0);
        }
    }

    // ---- final epilogue: +bbo, mish, transpose via LDS, coalesced float4 stores ----
    float4 bboq[4];
    #pragma unroll
    for (int s = 0; s < 4; ++s)
        bboq[s] = *reinterpret_cast<const float4*>(bbo + w*32 + qh*4 + s*8);

    float outs[2][16];
    #pragma unroll
    for (int nt = 0; nt < 2; ++nt) {
        #pragma unroll
        for (int s = 0; s < 4; ++s) {
            const float* bp = (const float*)&bboq[s];
            #pragma unroll
            for (int r = 0; r < 4; ++r) {
                float x = acc2[nt][s*4+r] + bp[r];
                float e = __expf(x);
                float u = 1.f + e, u2 = u*u;
                outs[nt][s*4+r] = (x > 15.f) ? x : x * (u2 - 1.f) / (u2 + 1.f);
            }
        }
    }

    __syncthreads();   // all lP reads done; smem free for lT
    #pragma unroll
    for (int nt = 0; nt < 2; ++nt) {
        int m = nt*32 + l31;
        #pragma unroll
        for (int s = 0; s < 4; ++s)
            #pragma unroll
            for (int r = 0; r < 4; ++r)
                lT[m*LDK + w*32 + qh*4 + s*8 + r] = outs[nt][s*4+r];
    }
    __syncthreads();
    #pragma unroll
    for (int i = 0; i < 8; ++i) {
        int flat = i*1024 + tid*4;
        int r = flat >> 7, c = flat & 127;
        *reinterpret_cast<float4*>(bias_out + (row0 + r)*128 + c) =
            *reinterpret_cast<const float4*>(&lT[r*LDK + c]);
    }
}

// ---------------- QK^T logits (in-place over diffs): logits = pq.pk/sqrt(D) + diffs ----------------
__global__ __launch_bounds__(256) void qk_kernel(
    const float* __restrict__ pq, const float* __restrict__ pk,
    float* __restrict__ logits)
{
    __shared__ float A[64*128];
    __shared__ float BT[128*64];
    int blk = blockIdx.x;
    int kt = blk & 7, h = (blk >> 3) & 3, qt = blk >> 5;
    int tid = threadIdx.x;

    #pragma unroll
    for (int i = 0; i < 8; ++i) {
        int flat = i*1024 + tid*4;
        int r = flat >> 7, c = flat & 127;
        *reinterpret_cast<float4*>(&A[flat]) =
            *reinterpret_cast<const float4*>(pq + (size_t)(qt*64 + r)*512 + h*128 + c);
    }
    {
        int kk = tid & 63, g = tid >> 6;
        #pragma unroll
        for (int i = 0; i < 8; ++i) {
            int d0 = g*32 + i*4;
            float4 vv = *reinterpret_cast<const float4*>(pk + (size_t)(kt*64 + kk)*512 + h*128 + d0);
            BT[(d0+0)*64 + kk] = vv.x;
            BT[(d0+1)*64 + kk] = vv.y;
            BT[(d0+2)*64 + kk] = vv.z;
            BT[(d0+3)*64 + kk] = vv.w;
        }
    }
    __syncthreads();

    int qg = tid >> 4, kg = tid & 15;
    int qs = qg*4, ks = kg*4;
    float acc[4][4] = {};
    for (int d = 0; d < 128; d += 4) {
        float a_[4][4], b_[4][4];
        #pragma unroll
        for (int i = 0; i < 4; ++i) {
            float4 av = *reinterpret_cast<const float4*>(&A[(qs+i)*128 + d]);
            a_[i][0] = av.x; a_[i][1] = av.y; a_[i][2] = av.z; a_[i][3] = av.w;
        }
        #pragma unroll
        for (int dd = 0; dd < 4; ++dd) {
            float4 bv = *reinterpret_cast<const float4*>(&BT[(d+dd)*64 + ks]);
            b_[dd][0] = bv.x; b_[dd][1] = bv.y; b_[dd][2] = bv.z; b_[dd][3] = bv.w;
        }
        #pragma unroll
        for (int i = 0; i < 4; ++i)
            #pragma unroll
            for (int j = 0; j < 4; ++j)
                acc[i][j] += a_[i][0]*b_[0][j] + a_[i][1]*b_[1][j]
                           + a_[i][2]*b_[2][j] + a_[i][3]*b_[3][j];
    }

    const float scale = 0.088388347648318447f;   // 1/sqrt(128)
    #pragma unroll
    for (int i = 0; i < 4; ++i) {
        size_t off = (size_t)h*MROWS + (size_t)(qt*64 + qs + i)*512 + kt*64 + ks;
        float4* p = reinterpret_cast<float4*>(logits + off);
        float4 dv = *p;
        dv.x = fmaf(acc[i][0], scale, dv.x);
        dv.y = fmaf(acc[i][1], scale, dv.y);
        dv.z = fmaf(acc[i][2], scale, dv.z);
        dv.w = fmaf(acc[i][3], scale, dv.w);
        *p = dv;
    }
}

// ---------------- softmax + v reduction -> vals_mean ----------------
__global__ __launch_bounds__(256) void attnval_kernel(
    const float* __restrict__ logits, const float* __restrict__ v,
    float* __restrict__ vmean)
{
    __shared__ float red[32];
    int qrow = blockIdx.x, tid = threadIdx.x;
    int wid = tid >> 6;
    float vsum = 0.f;
    float v0 = v[tid], v1 = v[tid + 256];
    for (int h = 0; h < 4; ++h) {
        const float* lr = logits + (size_t)h*MROWS + (size_t)qrow*512;
        float l0 = lr[tid], l1 = lr[tid + 256];
        float m = fmaxf(l0, l1);
        #pragma unroll
        for (int o = 1; o < 64; o <<= 1) m = fmaxf(m, __shfl_xor(m, o));
        if ((tid & 63) == 0) red[wid] = m;
        __syncthreads();
        m = fmaxf(fmaxf(red[0], red[1]), fmaxf(red[2], red[3]));
        float e0 = __expf(l0 - m), e1 = __expf(l1 - m);
        float s = e0 + e1;
        float sv = e0*v0 + e1*v1;
        #pragma unroll
        for (int o = 1; o < 64; o <<= 1) { s += __shfl_xor(s, o); sv += __shfl_xor(sv, o); }
        __syncthreads();
        if ((tid & 63) == 0) { red[8 + wid] = s; red[16 + wid] = sv; }
        __syncthreads();
        float S  = red[8]  + red[9]  + red[10] + red[11];
        float SV = red[16] + red[17] + red[18] + red[19];
        vsum += SV / S;
        __syncthreads();
    }
    if (tid == 0) vmean[qrow] = vsum * 0.25f;
}

// ---------------- q_new/k_new: layernorm(x + mish(p_flat @ W.T + b)) ----------------
__global__ __launch_bounds__(256) void qkout_kernel(
    const float* __restrict__ p, const float* __restrict__ x,
    const float* __restrict__ W, const float* __restrict__ bo,
    const float* __restrict__ g, const float* __restrict__ be,
    float* __restrict__ out)
{
    __shared__ float pr[512];
    __shared__ float red[256];
    int n = blockIdx.x, tid = threadIdx.x;
    if (tid < 128)
        reinterpret_cast<float4*>(pr)[tid] = reinterpret_cast<const float4*>(p + (size_t)n*512)[tid];
    __syncthreads();
    int o = tid >> 2, part = tid & 3;
    const float4* wr = reinterpret_cast<const float4*>(W + o*512 + part*128);
    float acc = 0.f;
    #pragma unroll
    for (int c = 0; c < 32; ++c) {
        float4 w4 = wr[c];
        int base = part*32 + c;
        acc += pr[base]*w4.x + pr[128 + base]*w4.y + pr[256 + base]*w4.z + pr[384 + base]*w4.w;
    }
    red[tid] = acc;
    __syncthreads();
    if (tid < 64) {
        float s = red[tid*4] + red[tid*4+1] + red[tid*4+2] + red[tid*4+3] + bo[tid];
        float e = __expf(s);
        float u = 1.f + e, u2 = u*u;
        float msh = (s > 15.f) ? s : s * (u2 - 1.f) / (u2 + 1.f);
        float val = x[n*64 + tid] + msh;
        float m = val, m2 = val*val;
        #pragma unroll
        for (int off = 1; off < 64; off <<= 1) { m += __shfl_xor(m, off); m2 += __shfl_xor(m2, off); }
        m *= (1.f/64.f); m2 *= (1.f/64.f);
        float var = m2 - m*m;
        out[n*64 + tid] = (val - m) * rsqrtf(var + 1e-5f) * g[tid] + be[tid];
    }
}

extern "C" void kernel_launch(void* const* d_in, const int* in_sizes, int n_in,
                              void* d_out, int out_size, void* d_ws, size_t ws_size,
                              hipStream_t stream) {
    const float* q    = (const float*)d_in[0];
    const float* k    = (const float*)d_in[1];
    const float* v    = (const float*)d_in[2];
    const float* bias = (const float*)d_in[3];
    const float* Wq   = (const float*)d_in[4];
    const float* bq   = (const float*)d_in[5];
    const float* Wk   = (const float*)d_in[6];
    const float* bk   = (const float*)d_in[7];
    const float* Wqo  = (const float*)d_in[8];
    const float* bqo  = (const float*)d_in[9];
    const float* Wko  = (const float*)d_in[10];
    const float* bko  = (const float*)d_in[11];
    const float* qlg  = (const float*)d_in[12];
    const float* qlb  = (const float*)d_in[13];
    const float* klg  = (const float*)d_in[14];
    const float* klb  = (const float*)d_in[15];
    const float* Wb   = (const float*)d_in[16];
    const float* bb   = (const float*)d_in[17];
    const float* Wbo  = (const float*)d_in[18];
    const float* bbo  = (const float*)d_in[19];

    float* out = (float*)d_out;
    float* ws  = (float*)d_ws;
    float* diffs = ws;                                   // 4*262144 fp32 (also logits, in place)
    float* pq    = ws + 4*MROWS;                         // 262144
    float* pk    = pq + MROWS;                           // 262144
    unsigned short* wbf = (unsigned short*)(pk + MROWS); // 131072 bf16 (Wb | Wbo)

    float* q_new = out;             // 512*64
    float* k_new = out + 32768;     // 512*64
    float* vmean = out + 65536;     // 512
    float* b_out = out + 66048;     // 512*512*128

    pre_kernel<<<dim3(1536), dim3(256), 0, stream>>>(q, k, Wq, bq, Wk, bk, pq, pk, Wb, Wbo, wbf);
    bias_kernel<<<dim3(4096), dim3(256), 0, stream>>>(bias, wbf, bb, wbf + 65536, bbo, b_out, diffs);
    qk_kernel<<<dim3(256), dim3(256), 0, stream>>>(pq, pk, diffs);
    attnval_kernel<<<dim3(512), dim3(256), 0, stream>>>(diffs, v, vmean);
    qkout_kernel<<<dim3(512), dim3(256), 0, stream>>>(pq, q, Wqo, bqo, qlg, qlb, q_new);
    qkout_kernel<<<dim3(512), dim3(256), 0, stream>>>(pk, k, Wko, bko, klg, klb, k_new);
}